// Round 2
// baseline (665.835 us; speedup 1.0000x reference)
//
#include <hip/hip_runtime.h>
#include <float.h>

#define NUM_EMB 512
#define DIM     128
#define HWX     4096          // 64*64 spatial per batch
#define NPOS    (32 * 4096)   // 131072 positions
#define MARGIN  0.5f

// ---------------- workspace layout (bytes) ----------------
#define WS_ZT    ((size_t)0)                    // 131072*128 fp16 = 33554432
#define WS_E16   ((size_t)33554432)             // 512*128 fp16   = 131072
#define WS_ESQ   ((size_t)33685504)             // 512 fp32       = 2048
#define WS_GIDX  ((size_t)33687552)             // 131072 int     = 524288
#define WS_WL    ((size_t)34211840)             // 131072 int     = 524288
#define WS_CNT   ((size_t)34736128)             // counter        = 256
#define WS_NEED  ((size_t)34736384)

using half8 = __attribute__((ext_vector_type(8))) _Float16;
using f32x4 = __attribute__((ext_vector_type(4))) float;

// ---------------- prep: e16[k][c], exact e_sq, zero counter ----------------
__global__ void prep_kernel(const float* __restrict__ emb, _Float16* __restrict__ e16,
                            float* __restrict__ esq, int* __restrict__ cnt) {
    int k = blockIdx.x * blockDim.x + threadIdx.x;
    if (k == 0) *cnt = 0;
    if (k < NUM_EMB) {
        const float4* row = (const float4*)(emb + (size_t)k * DIM);
        _Float16* dst = e16 + (size_t)k * DIM;
        float s0 = 0.f, s1 = 0.f, s2 = 0.f, s3 = 0.f;
        #pragma unroll
        for (int c = 0; c < DIM / 4; ++c) {
            float4 v = row[c];
            s0 = fmaf(v.x, v.x, s0);
            s1 = fmaf(v.y, v.y, s1);
            s2 = fmaf(v.z, v.z, s2);
            s3 = fmaf(v.w, v.w, s3);
            dst[4 * c + 0] = (_Float16)v.x;
            dst[4 * c + 1] = (_Float16)v.y;
            dst[4 * c + 2] = (_Float16)v.z;
            dst[4 * c + 3] = (_Float16)v.w;
        }
        esq[k] = (s0 + s1) + (s2 + s3);   // identical math to round-1 (verified exact vs numpy)
    }
}

// ---------------- transpose: z (b,c,hw) fp32 -> zt (n,c) fp16 ----------------
__global__ __launch_bounds__(256) void transpose_kernel(const float* __restrict__ z,
                                                        _Float16* __restrict__ zt) {
    __shared__ __align__(16) _Float16 sh[64 * 136];   // 64 rows, 272B stride (pad 16B)
    int t = threadIdx.x;
    int n0 = blockIdx.x * 64;
    int b = n0 >> 12, hw0 = n0 & 4095;
    int q = t >> 6, l = t & 63;
    const float* src = z + (size_t)b * DIM * HWX + hw0 + l;
    #pragma unroll
    for (int i = 0; i < 32; ++i) {
        int c = q * 32 + i;
        float v = src[(size_t)c * HWX];           // 64 consecutive lanes -> coalesced
        sh[l * 136 + c] = (_Float16)v;
    }
    __syncthreads();
    #pragma unroll
    for (int r = 0; r < 4; ++r) {
        int f = r * 4096 + t * 16;                // byte offset in 16KB output tile
        int row = f >> 8, colb = f & 255;
        float4 v = *(const float4*)((const char*)sh + row * 272 + colb);
        *(float4*)((char*)(zt + (size_t)(n0 + row) * DIM) + colb) = v;  // contiguous writes
    }
}

// ---------------- main: MFMA GEMM + fused top-2 argmin ----------------
// block = 256 thr (4 waves), 128 positions x all 512 codes (4 tiles of 128).
// wave (wm,wn) owns 64 pos x 64 codes as 4x4 grid of 16x16x32 f16 MFMA.
__global__ __launch_bounds__(256) void gemm_argmin(const _Float16* __restrict__ zt,
                                                   const _Float16* __restrict__ e16,
                                                   const float* __restrict__ esq,
                                                   int* __restrict__ gidx,
                                                   int* __restrict__ wl,
                                                   int* __restrict__ cnt) {
    __shared__ __align__(16) _Float16 Ash[128 * 136];   // pos rows, 272B stride (2-way banks)
    __shared__ __align__(16) _Float16 Bsh[128 * 136];   // code rows
    __shared__ float mB1[2][128];
    __shared__ float mB2[2][128];
    __shared__ int   mBI[2][128];

    int t = threadIdx.x;
    int lane = t & 63, wave = t >> 6;
    int wm = wave & 1, wn = wave >> 1;
    int quad = lane >> 4, l15 = lane & 15;
    int n0 = blockIdx.x * 128;

    // stage A once: zt rows n0..n0+127 (contiguous 32KB) into padded LDS
    {
        const char* src = (const char*)(zt + (size_t)n0 * DIM);
        #pragma unroll
        for (int r = 0; r < 8; ++r) {
            int f = r * 4096 + t * 16;
            int row = f >> 8, colb = f & 255;
            float4 v = *(const float4*)(src + f);
            *(float4*)((char*)Ash + row * 272 + colb) = v;
        }
    }

    float b1[16], b2[16];
    int bidx[16];
    #pragma unroll
    for (int s = 0; s < 16; ++s) { b1[s] = 3.0e38f; b2[s] = 3.0e38f; bidx[s] = 0; }

    for (int tile = 0; tile < 4; ++tile) {
        __syncthreads();   // A visible (tile 0); Bsh reads of prev tile done (tile>0)
        {
            const char* src = (const char*)(e16 + (size_t)tile * 128 * DIM);
            #pragma unroll
            for (int r = 0; r < 8; ++r) {
                int f = r * 4096 + t * 16;
                int row = f >> 8, colb = f & 255;
                float4 v = *(const float4*)(src + f);
                *(float4*)((char*)Bsh + row * 272 + colb) = v;
            }
        }
        __syncthreads();

        float esqv[4]; int codev[4];
        #pragma unroll
        for (int nt = 0; nt < 4; ++nt) {
            int code = tile * 128 + wn * 64 + nt * 16 + l15;
            codev[nt] = code;
            esqv[nt] = esq[code];
        }

        f32x4 acc[4][4];
        #pragma unroll
        for (int mt = 0; mt < 4; ++mt)
            #pragma unroll
            for (int nt = 0; nt < 4; ++nt)
                acc[mt][nt] = (f32x4){0.f, 0.f, 0.f, 0.f};

        #pragma unroll
        for (int kc = 0; kc < 4; ++kc) {
            half8 af[4], bf[4];
            #pragma unroll
            for (int mt = 0; mt < 4; ++mt) {
                int m = wm * 64 + mt * 16 + l15;
                af[mt] = *(const half8*)((const char*)Ash + m * 272 + kc * 64 + quad * 16);
            }
            #pragma unroll
            for (int nt = 0; nt < 4; ++nt) {
                int n = wn * 64 + nt * 16 + l15;
                bf[nt] = *(const half8*)((const char*)Bsh + n * 272 + kc * 64 + quad * 16);
            }
            #pragma unroll
            for (int mt = 0; mt < 4; ++mt)
                #pragma unroll
                for (int nt = 0; nt < 4; ++nt)
                    acc[mt][nt] = __builtin_amdgcn_mfma_f32_16x16x32_f16(af[mt], bf[nt], acc[mt][nt], 0, 0, 0);
        }

        // fused top-2 update: 6 VALU/score; ascending code order => np first-min tiebreak
        #pragma unroll
        for (int mt = 0; mt < 4; ++mt)
            #pragma unroll
            for (int nt = 0; nt < 4; ++nt)
                #pragma unroll
                for (int r = 0; r < 4; ++r) {
                    int s = mt * 4 + r;
                    float sc = fmaf(-2.0f, acc[mt][nt][r], esqv[nt]);
                    float ob1 = b1[s];
                    b2[s] = fminf(b2[s], fmaxf(ob1, sc));
                    bool lt = sc < ob1;
                    b1[s] = lt ? sc : ob1;
                    bidx[s] = lt ? codev[nt] : bidx[s];
                }
    }

    // butterfly top-2 merge across the 16 lanes sharing each position
    #pragma unroll
    for (int d = 1; d < 16; d <<= 1) {
        #pragma unroll
        for (int s = 0; s < 16; ++s) {
            float ob1 = __shfl_xor(b1[s], d, 64);
            float ob2 = __shfl_xor(b2[s], d, 64);
            int   obi = __shfl_xor(bidx[s], d, 64);
            float nb2 = fminf(fminf(b2[s], ob2), fmaxf(b1[s], ob1));
            bool take = (ob1 < b1[s]) || (ob1 == b1[s] && obi < bidx[s]);
            b1[s] = take ? ob1 : b1[s];
            bidx[s] = take ? obi : bidx[s];
            b2[s] = nb2;
        }
    }
    if (l15 == 0) {
        #pragma unroll
        for (int s = 0; s < 16; ++s) {
            int m = wm * 64 + (s >> 2) * 16 + quad * 4 + (s & 3);
            mB1[wn][m] = b1[s]; mB2[wn][m] = b2[s]; mBI[wn][m] = bidx[s];
        }
    }
    __syncthreads();
    if (t < 128) {
        float a1 = mB1[0][t], a2 = mB2[0][t]; int ai = mBI[0][t];
        float c1 = mB1[1][t], c2 = mB2[1][t]; int ci = mBI[1][t];
        float f2 = fminf(fminf(a2, c2), fmaxf(a1, c1));
        bool take = (c1 < a1) || (c1 == a1 && ci < ai);
        float f1 = take ? c1 : a1;
        int   fi = take ? ci : ai;
        gidx[n0 + t] = fi;
        if (f2 - f1 < MARGIN) {
            int p = atomicAdd(cnt, 1);
            wl[p] = n0 + t;
        }
    }
}

// ---------------- refine: exact fp32 rescan for flagged positions ----------------
// one wave <- 4 entries; identical partial-sum structure as round-1 (verified exact)
__global__ __launch_bounds__(256) void refine_kernel(const float* __restrict__ z,
                                                     const float* __restrict__ emb,
                                                     const float* __restrict__ esq,
                                                     const int* __restrict__ wl,
                                                     const int* __restrict__ cnt,
                                                     int* __restrict__ gidx) {
    __shared__ float zsh[4][4][128];
    int t = threadIdx.x, lane = t & 63, wave = t >> 6;
    int count = *cnt;                 // uniform across grid
    if (count == 0) return;           // uniform exit
    int iters = (count + 8191) / 8192;   // grid 512 blocks * 16 entries
    for (int it = 0; it < iters; ++it) {
        int ebase = it * 8192 + blockIdx.x * 16 + wave * 4;
        int nidx[4];
        #pragma unroll
        for (int j = 0; j < 4; ++j) {
            int e = ebase + j;
            if (e > count - 1) e = count - 1;   // duplicates benign (same value rewritten)
            int n = wl[e];
            nidx[j] = n;
            int b = n >> 12, hw = n & 4095;
            const float* zp = z + (size_t)b * DIM * HWX + hw;
            zsh[wave][j][lane]      = zp[(size_t)lane * HWX];
            zsh[wave][j][lane + 64] = zp[(size_t)(lane + 64) * HWX];
        }
        __syncthreads();
        #pragma unroll
        for (int j = 0; j < 4; ++j) {
            float best = 3.0e38f; int bi = 0;
            for (int j2 = 0; j2 < 8; ++j2) {
                int k = j2 * 64 + lane;
                const float4* er = (const float4*)(emb + (size_t)k * DIM);
                float d0 = 0.f, d1 = 0.f, d2 = 0.f, d3 = 0.f;
                #pragma unroll
                for (int cq = 0; cq < 32; ++cq) {
                    float4 e4 = er[cq];
                    float4 z4 = *(const float4*)&zsh[wave][j][cq * 4];  // broadcast read
                    d0 = fmaf(z4.x, e4.x, d0);
                    d1 = fmaf(z4.y, e4.y, d1);
                    d2 = fmaf(z4.z, e4.z, d2);
                    d3 = fmaf(z4.w, e4.w, d3);
                }
                float s = esq[k] - 2.f * ((d0 + d1) + (d2 + d3));
                if (s < best) { best = s; bi = k; }   // per-lane ks ascending
            }
            // lexicographic (s,k) min across 64 lanes
            #pragma unroll
            for (int d = 1; d < 64; d <<= 1) {
                float ob = __shfl_xor(best, d, 64);
                int   oi = __shfl_xor(bi, d, 64);
                bool take = (ob < best) || (ob == best && oi < bi);
                best = take ? ob : best;
                bi = take ? oi : bi;
            }
            if (lane == 0) gidx[nidx[j]] = bi;
        }
        __syncthreads();
    }
}

// ---------------- gather: out[b,c,hw] = emb[gidx[n], c] ----------------
__global__ __launch_bounds__(256) void gather_kernel(const float* __restrict__ emb,
                                                     const int* __restrict__ gidx,
                                                     float* __restrict__ out) {
    int n = blockIdx.x * 256 + threadIdx.x;
    int b = n >> 12, hw = n & 4095;
    int idx = gidx[n];
    float* ob = out + (size_t)b * DIM * HWX + hw;
    const float4* sel = (const float4*)(emb + (size_t)idx * DIM);
    #pragma unroll
    for (int c4 = 0; c4 < DIM / 4; ++c4) {
        float4 v = sel[c4];
        ob[(size_t)(4 * c4 + 0) * HWX] = v.x;
        ob[(size_t)(4 * c4 + 1) * HWX] = v.y;
        ob[(size_t)(4 * c4 + 2) * HWX] = v.z;
        ob[(size_t)(4 * c4 + 3) * HWX] = v.w;
    }
}

// ---------------- legacy fallback (round-1, verified) ----------------
__global__ void esq_kernel(const float* __restrict__ emb, float* __restrict__ e_sq) {
    int k = blockIdx.x * blockDim.x + threadIdx.x;
    if (k < NUM_EMB) {
        const float4* row = (const float4*)(emb + k * DIM);
        float s0 = 0.f, s1 = 0.f, s2 = 0.f, s3 = 0.f;
        #pragma unroll
        for (int c = 0; c < DIM / 4; ++c) {
            float4 v = row[c];
            s0 = fmaf(v.x, v.x, s0); s1 = fmaf(v.y, v.y, s1);
            s2 = fmaf(v.z, v.z, s2); s3 = fmaf(v.w, v.w, s3);
        }
        e_sq[k] = (s0 + s1) + (s2 + s3);
    }
}

__global__ __launch_bounds__(256) void vq_kernel(const float* __restrict__ z,
                                                 const float* __restrict__ emb,
                                                 const float* __restrict__ e_sq,
                                                 float* __restrict__ out) {
    int n = blockIdx.x * 256 + threadIdx.x;
    int b = n >> 12, hw = n & 4095;
    const float* zb = z + (size_t)b * DIM * HWX + hw;
    float zr[DIM];
    #pragma unroll
    for (int c = 0; c < DIM; ++c) zr[c] = zb[(size_t)c * HWX];
    float best = FLT_MAX; int besti = 0;
    for (int k = 0; k < NUM_EMB; ++k) {
        const float4* er = (const float4*)(emb + k * DIM);
        float d0 = 0.f, d1 = 0.f, d2 = 0.f, d3 = 0.f;
        #pragma unroll
        for (int c = 0; c < DIM / 4; ++c) {
            float4 e = er[c];
            d0 = fmaf(zr[4 * c + 0], e.x, d0);
            d1 = fmaf(zr[4 * c + 1], e.y, d1);
            d2 = fmaf(zr[4 * c + 2], e.z, d2);
            d3 = fmaf(zr[4 * c + 3], e.w, d3);
        }
        float s = e_sq[k] - 2.f * ((d0 + d1) + (d2 + d3));
        if (s < best) { best = s; besti = k; }
    }
    float* ob = out + (size_t)b * DIM * HWX + hw;
    const float4* sel = (const float4*)(emb + (size_t)besti * DIM);
    #pragma unroll
    for (int c4 = 0; c4 < DIM / 4; ++c4) {
        float4 v = sel[c4];
        ob[(size_t)(4 * c4 + 0) * HWX] = v.x;
        ob[(size_t)(4 * c4 + 1) * HWX] = v.y;
        ob[(size_t)(4 * c4 + 2) * HWX] = v.z;
        ob[(size_t)(4 * c4 + 3) * HWX] = v.w;
    }
}

extern "C" void kernel_launch(void* const* d_in, const int* in_sizes, int n_in,
                              void* d_out, int out_size, void* d_ws, size_t ws_size,
                              hipStream_t stream) {
    const float* z   = (const float*)d_in[0];   // (32,128,64,64) fp32
    const float* emb = (const float*)d_in[1];   // (512,128) fp32
    float* out = (float*)d_out;

    if (ws_size < WS_NEED) {
        // fallback: verified round-1 path
        float* e_sq = (float*)d_ws;
        esq_kernel<<<(NUM_EMB + 255) / 256, 256, 0, stream>>>(emb, e_sq);
        vq_kernel<<<NPOS / 256, 256, 0, stream>>>(z, emb, e_sq, out);
        return;
    }

    char* ws = (char*)d_ws;
    _Float16* zt  = (_Float16*)(ws + WS_ZT);
    _Float16* e16 = (_Float16*)(ws + WS_E16);
    float*    esq = (float*)(ws + WS_ESQ);
    int*      gidx = (int*)(ws + WS_GIDX);
    int*      wl   = (int*)(ws + WS_WL);
    int*      cnt  = (int*)(ws + WS_CNT);

    prep_kernel<<<2, 256, 0, stream>>>(emb, e16, esq, cnt);
    transpose_kernel<<<NPOS / 64, 256, 0, stream>>>(z, zt);
    gemm_argmin<<<NPOS / 128, 256, 0, stream>>>(zt, e16, esq, gidx, wl, cnt);
    refine_kernel<<<512, 256, 0, stream>>>(z, emb, esq, wl, cnt, gidx);
    gather_kernel<<<NPOS / 256, 256, 0, stream>>>(emb, gidx, out);
}

// Round 3
// 314.543 us; speedup vs baseline: 2.1168x; 2.1168x over previous
//
#include <hip/hip_runtime.h>
#include <float.h>

#define NUM_EMB 512
#define DIM     128
#define HWX     4096          // 64*64 spatial per batch
#define NPOS    (32 * 4096)   // 131072 positions
#define MARGIN  0.25f         // ~14 sigma of fp16-score-difference noise (std ~0.018)

// ---------------- workspace layout (bytes) ----------------
#define WS_ZT    ((size_t)0)                    // 131072*128 fp16 = 33554432
#define WS_E16   ((size_t)33554432)             // 512*128 fp16   = 131072
#define WS_ESQ   ((size_t)33685504)             // 512 fp32       = 2048
#define WS_GIDX  ((size_t)33687552)             // 131072 int     = 524288
#define WS_WL    ((size_t)34211840)             // 131072 int     = 524288
#define WS_CNT   ((size_t)34736128)             // counter        = 256
#define WS_NEED  ((size_t)34736384)

using half8 = __attribute__((ext_vector_type(8))) _Float16;
using f32x4 = __attribute__((ext_vector_type(4))) float;

// ---------------- prep: e16[k][c], exact e_sq, zero counter ----------------
__global__ void prep_kernel(const float* __restrict__ emb, _Float16* __restrict__ e16,
                            float* __restrict__ esq, int* __restrict__ cnt) {
    int k = blockIdx.x * blockDim.x + threadIdx.x;
    if (k == 0) *cnt = 0;
    if (k < NUM_EMB) {
        const float4* row = (const float4*)(emb + (size_t)k * DIM);
        _Float16* dst = e16 + (size_t)k * DIM;
        float s0 = 0.f, s1 = 0.f, s2 = 0.f, s3 = 0.f;
        #pragma unroll
        for (int c = 0; c < DIM / 4; ++c) {
            float4 v = row[c];
            s0 = fmaf(v.x, v.x, s0);
            s1 = fmaf(v.y, v.y, s1);
            s2 = fmaf(v.z, v.z, s2);
            s3 = fmaf(v.w, v.w, s3);
            dst[4 * c + 0] = (_Float16)v.x;
            dst[4 * c + 1] = (_Float16)v.y;
            dst[4 * c + 2] = (_Float16)v.z;
            dst[4 * c + 3] = (_Float16)v.w;
        }
        esq[k] = (s0 + s1) + (s2 + s3);   // identical math to round-1 (verified exact vs numpy)
    }
}

// ---------------- transpose: z (b,c,hw) fp32 -> zt (n,c) fp16 ----------------
__global__ __launch_bounds__(256) void transpose_kernel(const float* __restrict__ z,
                                                        _Float16* __restrict__ zt) {
    __shared__ __align__(16) _Float16 sh[64 * 136];   // 64 rows, 272B stride (pad 16B)
    int t = threadIdx.x;
    int n0 = blockIdx.x * 64;
    int b = n0 >> 12, hw0 = n0 & 4095;
    int q = t >> 6, l = t & 63;
    const float* src = z + (size_t)b * DIM * HWX + hw0 + l;
    #pragma unroll
    for (int i = 0; i < 32; ++i) {
        int c = q * 32 + i;
        float v = src[(size_t)c * HWX];           // 64 consecutive lanes -> coalesced
        sh[l * 136 + c] = (_Float16)v;
    }
    __syncthreads();
    #pragma unroll
    for (int r = 0; r < 4; ++r) {
        int f = r * 4096 + t * 16;                // byte offset in 16KB output tile
        int row = f >> 8, colb = f & 255;
        float4 v = *(const float4*)((const char*)sh + row * 272 + colb);
        *(float4*)((char*)(zt + (size_t)(n0 + row) * DIM) + colb) = v;  // contiguous writes
    }
}

// ---------------- main: MFMA GEMM + fused top-2 argmin ----------------
// block = 256 thr (4 waves), 128 positions x all 512 codes (4 tiles of 128).
// wave (wm,wn) owns 64 pos x 64 codes as 4x4 grid of 16x16x32 f16 MFMA.
__global__ __launch_bounds__(256) void gemm_argmin(const _Float16* __restrict__ zt,
                                                   const _Float16* __restrict__ e16,
                                                   const float* __restrict__ esq,
                                                   int* __restrict__ gidx,
                                                   int* __restrict__ wl,
                                                   int* __restrict__ cnt) {
    __shared__ __align__(16) _Float16 Ash[128 * 136];   // pos rows, 272B stride (2-way banks)
    __shared__ __align__(16) _Float16 Bsh[128 * 136];   // code rows
    __shared__ float mB1[2][128];
    __shared__ float mB2[2][128];
    __shared__ int   mBI[2][128];

    int t = threadIdx.x;
    int lane = t & 63, wave = t >> 6;
    int wm = wave & 1, wn = wave >> 1;
    int quad = lane >> 4, l15 = lane & 15;
    int n0 = blockIdx.x * 128;

    // stage A once: zt rows n0..n0+127 (contiguous 32KB) into padded LDS
    {
        const char* src = (const char*)(zt + (size_t)n0 * DIM);
        #pragma unroll
        for (int r = 0; r < 8; ++r) {
            int f = r * 4096 + t * 16;
            int row = f >> 8, colb = f & 255;
            float4 v = *(const float4*)(src + f);
            *(float4*)((char*)Ash + row * 272 + colb) = v;
        }
    }

    float b1[16], b2[16];
    int bidx[16];
    #pragma unroll
    for (int s = 0; s < 16; ++s) { b1[s] = 3.0e38f; b2[s] = 3.0e38f; bidx[s] = 0; }

    for (int tile = 0; tile < 4; ++tile) {
        __syncthreads();   // A visible (tile 0); Bsh reads of prev tile done (tile>0)
        {
            const char* src = (const char*)(e16 + (size_t)tile * 128 * DIM);
            #pragma unroll
            for (int r = 0; r < 8; ++r) {
                int f = r * 4096 + t * 16;
                int row = f >> 8, colb = f & 255;
                float4 v = *(const float4*)(src + f);
                *(float4*)((char*)Bsh + row * 272 + colb) = v;
            }
        }
        __syncthreads();

        float esqv[4]; int codev[4];
        #pragma unroll
        for (int nt = 0; nt < 4; ++nt) {
            int code = tile * 128 + wn * 64 + nt * 16 + l15;
            codev[nt] = code;
            esqv[nt] = esq[code];
        }

        f32x4 acc[4][4];
        #pragma unroll
        for (int mt = 0; mt < 4; ++mt)
            #pragma unroll
            for (int nt = 0; nt < 4; ++nt)
                acc[mt][nt] = (f32x4){0.f, 0.f, 0.f, 0.f};

        #pragma unroll
        for (int kc = 0; kc < 4; ++kc) {
            half8 af[4], bf[4];
            #pragma unroll
            for (int mt = 0; mt < 4; ++mt) {
                int m = wm * 64 + mt * 16 + l15;
                af[mt] = *(const half8*)((const char*)Ash + m * 272 + kc * 64 + quad * 16);
            }
            #pragma unroll
            for (int nt = 0; nt < 4; ++nt) {
                int n = wn * 64 + nt * 16 + l15;
                bf[nt] = *(const half8*)((const char*)Bsh + n * 272 + kc * 64 + quad * 16);
            }
            #pragma unroll
            for (int mt = 0; mt < 4; ++mt)
                #pragma unroll
                for (int nt = 0; nt < 4; ++nt)
                    acc[mt][nt] = __builtin_amdgcn_mfma_f32_16x16x32_f16(af[mt], bf[nt], acc[mt][nt], 0, 0, 0);
        }

        // fused top-2 update: 6 VALU/score; ascending code order => np first-min tiebreak
        #pragma unroll
        for (int mt = 0; mt < 4; ++mt)
            #pragma unroll
            for (int nt = 0; nt < 4; ++nt)
                #pragma unroll
                for (int r = 0; r < 4; ++r) {
                    int s = mt * 4 + r;
                    float sc = fmaf(-2.0f, acc[mt][nt][r], esqv[nt]);
                    float ob1 = b1[s];
                    b2[s] = fminf(b2[s], fmaxf(ob1, sc));
                    bool lt = sc < ob1;
                    b1[s] = lt ? sc : ob1;
                    bidx[s] = lt ? codev[nt] : bidx[s];
                }
    }

    // butterfly top-2 merge across the 16 lanes sharing each position
    #pragma unroll
    for (int d = 1; d < 16; d <<= 1) {
        #pragma unroll
        for (int s = 0; s < 16; ++s) {
            float ob1 = __shfl_xor(b1[s], d, 64);
            float ob2 = __shfl_xor(b2[s], d, 64);
            int   obi = __shfl_xor(bidx[s], d, 64);
            float nb2 = fminf(fminf(b2[s], ob2), fmaxf(b1[s], ob1));
            bool take = (ob1 < b1[s]) || (ob1 == b1[s] && obi < bidx[s]);
            b1[s] = take ? ob1 : b1[s];
            bidx[s] = take ? obi : bidx[s];
            b2[s] = nb2;
        }
    }
    if (l15 == 0) {
        #pragma unroll
        for (int s = 0; s < 16; ++s) {
            int m = wm * 64 + (s >> 2) * 16 + quad * 4 + (s & 3);
            mB1[wn][m] = b1[s]; mB2[wn][m] = b2[s]; mBI[wn][m] = bidx[s];
        }
    }
    __syncthreads();
    if (t < 128) {
        float a1 = mB1[0][t], a2 = mB2[0][t]; int ai = mBI[0][t];
        float c1 = mB1[1][t], c2 = mB2[1][t]; int ci = mBI[1][t];
        float f2 = fminf(fminf(a2, c2), fmaxf(a1, c1));
        bool take = (c1 < a1) || (c1 == a1 && ci < ai);
        float f1 = take ? c1 : a1;
        int   fi = take ? ci : ai;
        gidx[n0 + t] = fi;
        if (f2 - f1 < MARGIN) {
            int p = atomicAdd(cnt, 1);
            wl[p] = n0 + t;
        }
    }
}

// ---------------- refine v2: exact fp32 rescan, LDS-tiled codebook ----------------
// 256 blocks x 4 waves x RB entries per pass = 4096 entries/pass (uniform pass count
// across the grid -> barrier-safe). Codebook staged per block in 8 tiles of 64 codes
// (coalesced float4 reads, pad-65 LDS layout: conflict-free lane-per-code reads).
// All 4 waves x RB entries share each staged tile.
// Partial-sum order (d0..d3 interleaved over q) identical to round-1-verified math.
#define RB 4
__global__ __launch_bounds__(256) void refine_kernel(const float* __restrict__ z,
                                                     const float* __restrict__ emb,
                                                     const float* __restrict__ esq,
                                                     const int* __restrict__ wl,
                                                     const int* __restrict__ cnt,
                                                     int* __restrict__ gidx) {
    __shared__ __align__(16) float esh[DIM][65];      // [dim][code], pad 65: write 4-way, read conflict-free
    __shared__ __align__(16) float zsh[4][RB][DIM];   // per-wave z rows
    int t = threadIdx.x, lane = t & 63, wave = t >> 6;
    int count = *cnt;
    int passes = (count + 4095) >> 12;
    for (int p = 0; p < passes; ++p) {
        int ebase = p * 4096 + blockIdx.x * 16 + wave * RB;
        int nn[RB]; bool act[RB];
        #pragma unroll
        for (int j = 0; j < RB; ++j) {
            int e = ebase + j;
            act[j] = e < count;
            if (e > count - 1) e = count - 1;   // clamp: duplicate work only in last partial pass
            int n = wl[e];
            nn[j] = n;
            int b = n >> 12, hw = n & 4095;
            const float* zp = z + (size_t)b * DIM * HWX + hw;
            zsh[wave][j][lane]      = zp[(size_t)lane * HWX];
            zsh[wave][j][lane + 64] = zp[(size_t)(lane + 64) * HWX];
        }
        float best[RB]; int bi[RB];
        #pragma unroll
        for (int j = 0; j < RB; ++j) { best[j] = 3.0e38f; bi[j] = 0; }

        for (int tile = 0; tile < 8; ++tile) {
            __syncthreads();                          // prev-tile reads done (also orders zsh writes, tile 0)
            {   // stage 64 codes x 128 dims: 2048 float4, flat-coalesced global reads
                const float4* gsrc = (const float4*)(emb + (size_t)tile * 64 * DIM);
                #pragma unroll
                for (int jj = 0; jj < 8; ++jj) {
                    int f = jj * 256 + t;
                    float4 v = gsrc[f];
                    int k = f >> 5, q = f & 31;
                    esh[4 * q + 0][k] = v.x;
                    esh[4 * q + 1][k] = v.y;
                    esh[4 * q + 2][k] = v.z;
                    esh[4 * q + 3][k] = v.w;
                }
            }
            __syncthreads();

            int k = tile * 64 + lane;                 // one code per lane
            float es = esq[k];
            float d[RB][4];
            #pragma unroll
            for (int j = 0; j < RB; ++j)
                #pragma unroll
                for (int i = 0; i < 4; ++i) d[j][i] = 0.f;

            #pragma unroll 8
            for (int q = 0; q < 32; ++q) {
                float e0 = esh[4 * q + 0][lane];      // banks (lane + const)%32: conflict-free
                float e1 = esh[4 * q + 1][lane];
                float e2 = esh[4 * q + 2][lane];
                float e3 = esh[4 * q + 3][lane];
                #pragma unroll
                for (int j = 0; j < RB; ++j) {
                    float4 zv = *(const float4*)&zsh[wave][j][q * 4];   // broadcast read
                    d[j][0] = fmaf(zv.x, e0, d[j][0]);
                    d[j][1] = fmaf(zv.y, e1, d[j][1]);
                    d[j][2] = fmaf(zv.z, e2, d[j][2]);
                    d[j][3] = fmaf(zv.w, e3, d[j][3]);
                }
            }
            #pragma unroll
            for (int j = 0; j < RB; ++j) {
                float s = es - 2.f * ((d[j][0] + d[j][1]) + (d[j][2] + d[j][3]));
                if (s < best[j]) { best[j] = s; bi[j] = k; }   // k ascending over tiles
            }
        }
        // lexicographic (s, k) argmin across 64 lanes = global first-min over 512 codes
        #pragma unroll
        for (int j = 0; j < RB; ++j) {
            #pragma unroll
            for (int dlt = 1; dlt < 64; dlt <<= 1) {
                float ob = __shfl_xor(best[j], dlt, 64);
                int   oi = __shfl_xor(bi[j], dlt, 64);
                bool take = (ob < best[j]) || (ob == best[j] && oi < bi[j]);
                best[j] = take ? ob : best[j];
                bi[j]   = take ? oi : bi[j];
            }
            if (lane == 0 && act[j]) gidx[nn[j]] = bi[j];
        }
    }
}

// ---------------- gather: out[b,c,hw] = emb[gidx[n], c] ----------------
__global__ __launch_bounds__(256) void gather_kernel(const float* __restrict__ emb,
                                                     const int* __restrict__ gidx,
                                                     float* __restrict__ out) {
    int n = blockIdx.x * 256 + threadIdx.x;
    int b = n >> 12, hw = n & 4095;
    int idx = gidx[n];
    float* ob = out + (size_t)b * DIM * HWX + hw;
    const float4* sel = (const float4*)(emb + (size_t)idx * DIM);
    #pragma unroll
    for (int c4 = 0; c4 < DIM / 4; ++c4) {
        float4 v = sel[c4];
        ob[(size_t)(4 * c4 + 0) * HWX] = v.x;
        ob[(size_t)(4 * c4 + 1) * HWX] = v.y;
        ob[(size_t)(4 * c4 + 2) * HWX] = v.z;
        ob[(size_t)(4 * c4 + 3) * HWX] = v.w;
    }
}

// ---------------- legacy fallback (round-1, verified) ----------------
__global__ void esq_kernel(const float* __restrict__ emb, float* __restrict__ e_sq) {
    int k = blockIdx.x * blockDim.x + threadIdx.x;
    if (k < NUM_EMB) {
        const float4* row = (const float4*)(emb + k * DIM);
        float s0 = 0.f, s1 = 0.f, s2 = 0.f, s3 = 0.f;
        #pragma unroll
        for (int c = 0; c < DIM / 4; ++c) {
            float4 v = row[c];
            s0 = fmaf(v.x, v.x, s0); s1 = fmaf(v.y, v.y, s1);
            s2 = fmaf(v.z, v.z, s2); s3 = fmaf(v.w, v.w, s3);
        }
        e_sq[k] = (s0 + s1) + (s2 + s3);
    }
}

__global__ __launch_bounds__(256) void vq_kernel(const float* __restrict__ z,
                                                 const float* __restrict__ emb,
                                                 const float* __restrict__ e_sq,
                                                 float* __restrict__ out) {
    int n = blockIdx.x * 256 + threadIdx.x;
    int b = n >> 12, hw = n & 4095;
    const float* zb = z + (size_t)b * DIM * HWX + hw;
    float zr[DIM];
    #pragma unroll
    for (int c = 0; c < DIM; ++c) zr[c] = zb[(size_t)c * HWX];
    float best = FLT_MAX; int besti = 0;
    for (int k = 0; k < NUM_EMB; ++k) {
        const float4* er = (const float4*)(emb + k * DIM);
        float d0 = 0.f, d1 = 0.f, d2 = 0.f, d3 = 0.f;
        #pragma unroll
        for (int c = 0; c < DIM / 4; ++c) {
            float4 e = er[c];
            d0 = fmaf(zr[4 * c + 0], e.x, d0);
            d1 = fmaf(zr[4 * c + 1], e.y, d1);
            d2 = fmaf(zr[4 * c + 2], e.z, d2);
            d3 = fmaf(zr[4 * c + 3], e.w, d3);
        }
        float s = e_sq[k] - 2.f * ((d0 + d1) + (d2 + d3));
        if (s < best) { best = s; besti = k; }
    }
    float* ob = out + (size_t)b * DIM * HWX + hw;
    const float4* sel = (const float4*)(emb + (size_t)besti * DIM);
    #pragma unroll
    for (int c4 = 0; c4 < DIM / 4; ++c4) {
        float4 v = sel[c4];
        ob[(size_t)(4 * c4 + 0) * HWX] = v.x;
        ob[(size_t)(4 * c4 + 1) * HWX] = v.y;
        ob[(size_t)(4 * c4 + 2) * HWX] = v.z;
        ob[(size_t)(4 * c4 + 3) * HWX] = v.w;
    }
}

extern "C" void kernel_launch(void* const* d_in, const int* in_sizes, int n_in,
                              void* d_out, int out_size, void* d_ws, size_t ws_size,
                              hipStream_t stream) {
    const float* z   = (const float*)d_in[0];   // (32,128,64,64) fp32
    const float* emb = (const float*)d_in[1];   // (512,128) fp32
    float* out = (float*)d_out;

    if (ws_size < WS_NEED) {
        // fallback: verified round-1 path
        float* e_sq = (float*)d_ws;
        esq_kernel<<<(NUM_EMB + 255) / 256, 256, 0, stream>>>(emb, e_sq);
        vq_kernel<<<NPOS / 256, 256, 0, stream>>>(z, emb, e_sq, out);
        return;
    }

    char* ws = (char*)d_ws;
    _Float16* zt  = (_Float16*)(ws + WS_ZT);
    _Float16* e16 = (_Float16*)(ws + WS_E16);
    float*    esq = (float*)(ws + WS_ESQ);
    int*      gidx = (int*)(ws + WS_GIDX);
    int*      wl   = (int*)(ws + WS_WL);
    int*      cnt  = (int*)(ws + WS_CNT);

    prep_kernel<<<2, 256, 0, stream>>>(emb, e16, esq, cnt);
    transpose_kernel<<<NPOS / 64, 256, 0, stream>>>(z, zt);
    gemm_argmin<<<NPOS / 128, 256, 0, stream>>>(zt, e16, esq, gidx, wl, cnt);
    refine_kernel<<<256, 256, 0, stream>>>(z, emb, esq, wl, cnt, gidx);
    gather_kernel<<<NPOS / 256, 256, 0, stream>>>(emb, gidx, out);
}

// Round 4
// 269.615 us; speedup vs baseline: 2.4696x; 1.1666x over previous
//
#include <hip/hip_runtime.h>
#include <float.h>

#define NUM_EMB 512
#define DIM     128
#define HWX     4096          // 64*64 spatial per batch
#define NPOS    (32 * 4096)   // 131072 positions
#define MARGIN  0.25f         // ~14 sigma of fp16-score-difference noise (std ~0.018)

// ---------------- workspace layout (bytes) ----------------
#define WS_ZT    ((size_t)0)                    // 131072*128 fp16 = 33554432
#define WS_E16   ((size_t)33554432)             // 512*128 fp16   = 131072
#define WS_ESQ   ((size_t)33685504)             // 512 fp32       = 2048
#define WS_GIDX  ((size_t)33687552)             // 131072 int     = 524288
#define WS_WL    ((size_t)34211840)             // 131072 int     = 524288
#define WS_CNT   ((size_t)34736128)             // counter        = 256
#define WS_NEED  ((size_t)34736384)

using half8 = __attribute__((ext_vector_type(8))) _Float16;
using f32x4 = __attribute__((ext_vector_type(4))) float;

// ---------------- prep: e16[k][c], exact e_sq, zero counter ----------------
__global__ void prep_kernel(const float* __restrict__ emb, _Float16* __restrict__ e16,
                            float* __restrict__ esq, int* __restrict__ cnt) {
    int k = blockIdx.x * blockDim.x + threadIdx.x;
    if (k == 0) *cnt = 0;
    if (k < NUM_EMB) {
        const float4* row = (const float4*)(emb + (size_t)k * DIM);
        _Float16* dst = e16 + (size_t)k * DIM;
        float s0 = 0.f, s1 = 0.f, s2 = 0.f, s3 = 0.f;
        #pragma unroll
        for (int c = 0; c < DIM / 4; ++c) {
            float4 v = row[c];
            s0 = fmaf(v.x, v.x, s0);
            s1 = fmaf(v.y, v.y, s1);
            s2 = fmaf(v.z, v.z, s2);
            s3 = fmaf(v.w, v.w, s3);
            dst[4 * c + 0] = (_Float16)v.x;
            dst[4 * c + 1] = (_Float16)v.y;
            dst[4 * c + 2] = (_Float16)v.z;
            dst[4 * c + 3] = (_Float16)v.w;
        }
        esq[k] = (s0 + s1) + (s2 + s3);   // identical math to round-1 (verified exact vs numpy)
    }
}

// ---------------- transpose: z (b,c,hw) fp32 -> zt (n,c) fp16 ----------------
__global__ __launch_bounds__(256) void transpose_kernel(const float* __restrict__ z,
                                                        _Float16* __restrict__ zt) {
    __shared__ __align__(16) _Float16 sh[64 * 136];   // 64 rows, 272B stride (pad 16B)
    int t = threadIdx.x;
    int n0 = blockIdx.x * 64;
    int b = n0 >> 12, hw0 = n0 & 4095;
    int q = t >> 6, l = t & 63;
    const float* src = z + (size_t)b * DIM * HWX + hw0 + l;
    #pragma unroll
    for (int i = 0; i < 32; ++i) {
        int c = q * 32 + i;
        float v = src[(size_t)c * HWX];           // 64 consecutive lanes -> coalesced
        sh[l * 136 + c] = (_Float16)v;
    }
    __syncthreads();
    #pragma unroll
    for (int r = 0; r < 4; ++r) {
        int f = r * 4096 + t * 16;                // byte offset in 16KB output tile
        int row = f >> 8, colb = f & 255;
        float4 v = *(const float4*)((const char*)sh + row * 272 + colb);
        *(float4*)((char*)(zt + (size_t)(n0 + row) * DIM) + colb) = v;  // contiguous writes
    }
}

// ---------------- main: MFMA GEMM + fused top-2 argmin ----------------
// block = 256 thr (4 waves), 128 positions x all 512 codes (4 tiles of 128).
// wave (wm,wn) owns 64 pos x 64 codes as 4x4 grid of 16x16x32 f16 MFMA.
__global__ __launch_bounds__(256) void gemm_argmin(const _Float16* __restrict__ zt,
                                                   const _Float16* __restrict__ e16,
                                                   const float* __restrict__ esq,
                                                   int* __restrict__ gidx,
                                                   int* __restrict__ wl,
                                                   int* __restrict__ cnt) {
    __shared__ __align__(16) _Float16 Ash[128 * 136];   // pos rows, 272B stride (2-way banks)
    __shared__ __align__(16) _Float16 Bsh[128 * 136];   // code rows
    __shared__ float mB1[2][128];
    __shared__ float mB2[2][128];
    __shared__ int   mBI[2][128];

    int t = threadIdx.x;
    int lane = t & 63, wave = t >> 6;
    int wm = wave & 1, wn = wave >> 1;
    int quad = lane >> 4, l15 = lane & 15;
    int n0 = blockIdx.x * 128;

    // stage A once: zt rows n0..n0+127 (contiguous 32KB) into padded LDS
    {
        const char* src = (const char*)(zt + (size_t)n0 * DIM);
        #pragma unroll
        for (int r = 0; r < 8; ++r) {
            int f = r * 4096 + t * 16;
            int row = f >> 8, colb = f & 255;
            float4 v = *(const float4*)(src + f);
            *(float4*)((char*)Ash + row * 272 + colb) = v;
        }
    }

    float b1[16], b2[16];
    int bidx[16];
    #pragma unroll
    for (int s = 0; s < 16; ++s) { b1[s] = 3.0e38f; b2[s] = 3.0e38f; bidx[s] = 0; }

    for (int tile = 0; tile < 4; ++tile) {
        __syncthreads();   // A visible (tile 0); Bsh reads of prev tile done (tile>0)
        {
            const char* src = (const char*)(e16 + (size_t)tile * 128 * DIM);
            #pragma unroll
            for (int r = 0; r < 8; ++r) {
                int f = r * 4096 + t * 16;
                int row = f >> 8, colb = f & 255;
                float4 v = *(const float4*)(src + f);
                *(float4*)((char*)Bsh + row * 272 + colb) = v;
            }
        }
        __syncthreads();

        float esqv[4]; int codev[4];
        #pragma unroll
        for (int nt = 0; nt < 4; ++nt) {
            int code = tile * 128 + wn * 64 + nt * 16 + l15;
            codev[nt] = code;
            esqv[nt] = esq[code];
        }

        f32x4 acc[4][4];
        #pragma unroll
        for (int mt = 0; mt < 4; ++mt)
            #pragma unroll
            for (int nt = 0; nt < 4; ++nt)
                acc[mt][nt] = (f32x4){0.f, 0.f, 0.f, 0.f};

        #pragma unroll
        for (int kc = 0; kc < 4; ++kc) {
            half8 af[4], bf[4];
            #pragma unroll
            for (int mt = 0; mt < 4; ++mt) {
                int m = wm * 64 + mt * 16 + l15;
                af[mt] = *(const half8*)((const char*)Ash + m * 272 + kc * 64 + quad * 16);
            }
            #pragma unroll
            for (int nt = 0; nt < 4; ++nt) {
                int n = wn * 64 + nt * 16 + l15;
                bf[nt] = *(const half8*)((const char*)Bsh + n * 272 + kc * 64 + quad * 16);
            }
            #pragma unroll
            for (int mt = 0; mt < 4; ++mt)
                #pragma unroll
                for (int nt = 0; nt < 4; ++nt)
                    acc[mt][nt] = __builtin_amdgcn_mfma_f32_16x16x32_f16(af[mt], bf[nt], acc[mt][nt], 0, 0, 0);
        }

        // fused top-2 update: 6 VALU/score; ascending code order => np first-min tiebreak
        #pragma unroll
        for (int mt = 0; mt < 4; ++mt)
            #pragma unroll
            for (int nt = 0; nt < 4; ++nt)
                #pragma unroll
                for (int r = 0; r < 4; ++r) {
                    int s = mt * 4 + r;
                    float sc = fmaf(-2.0f, acc[mt][nt][r], esqv[nt]);
                    float ob1 = b1[s];
                    b2[s] = fminf(b2[s], fmaxf(ob1, sc));
                    bool lt = sc < ob1;
                    b1[s] = lt ? sc : ob1;
                    bidx[s] = lt ? codev[nt] : bidx[s];
                }
    }

    // butterfly top-2 merge across the 16 lanes sharing each position
    #pragma unroll
    for (int d = 1; d < 16; d <<= 1) {
        #pragma unroll
        for (int s = 0; s < 16; ++s) {
            float ob1 = __shfl_xor(b1[s], d, 64);
            float ob2 = __shfl_xor(b2[s], d, 64);
            int   obi = __shfl_xor(bidx[s], d, 64);
            float nb2 = fminf(fminf(b2[s], ob2), fmaxf(b1[s], ob1));
            bool take = (ob1 < b1[s]) || (ob1 == b1[s] && obi < bidx[s]);
            b1[s] = take ? ob1 : b1[s];
            bidx[s] = take ? obi : bidx[s];
            b2[s] = nb2;
        }
    }
    if (l15 == 0) {
        #pragma unroll
        for (int s = 0; s < 16; ++s) {
            int m = wm * 64 + (s >> 2) * 16 + quad * 4 + (s & 3);
            mB1[wn][m] = b1[s]; mB2[wn][m] = b2[s]; mBI[wn][m] = bidx[s];
        }
    }
    __syncthreads();
    if (t < 128) {
        float a1 = mB1[0][t], a2 = mB2[0][t]; int ai = mBI[0][t];
        float c1 = mB1[1][t], c2 = mB2[1][t]; int ci = mBI[1][t];
        float f2 = fminf(fminf(a2, c2), fmaxf(a1, c1));
        bool take = (c1 < a1) || (c1 == a1 && ci < ai);
        float f1 = take ? c1 : a1;
        int   fi = take ? ci : ai;
        gidx[n0 + t] = fi;
        if (f2 - f1 < MARGIN) {
            int p = atomicAdd(cnt, 1);
            wl[p] = n0 + t;
        }
    }
}

// ---------------- refine v3: count-proportional GEMM-style exact rescan ----------------
// Block bi handles worklist entries [64*bi, 64*bi+64) (grid-strided). Per block:
// gather 64 flagged z rows (fp32) into LDS, then 8 coalesced codebook tiles of
// 64 codes x 128 dims fp32; each thread computes 4 entries x 4 codes with b128
// LDS reads (row stride 132 -> all read patterns 2-way/broadcast = free).
// Lex (s,k) reduction => numpy first-min tie-break.
__global__ __launch_bounds__(256) void refine_kernel(const float* __restrict__ z,
                                                     const float* __restrict__ emb,
                                                     const float* __restrict__ esq,
                                                     const int* __restrict__ wl,
                                                     const int* __restrict__ cnt,
                                                     int* __restrict__ gidx) {
    __shared__ __align__(16) float zsh[64][132];   // [entry][dim]
    __shared__ __align__(16) float esh[64][132];   // [code][dim], col 128 = esq
    __shared__ float rs[64][16];
    __shared__ int   ri[64][16];
    __shared__ int   nsh[64];

    int t = threadIdx.x, lane = t & 63, wave = t >> 6;
    int te = t & 15, tc = t >> 4;                  // entry group / code group
    int count = *cnt;

    for (int base = blockIdx.x * 64; base < count; base += 256 * 64) {
        // ---- gather 64 flagged z rows: wave w stages entries w*16..w*16+15 ----
        // 32 scattered 64-lane loads in flight per wave; LDS stores conflict-free.
        for (int j16 = 0; j16 < 16; ++j16) {
            int e = wave * 16 + j16;
            int ge = base + e;
            if (ge > count - 1) ge = count - 1;    // clamp: duplicate entries benign
            int n = wl[ge];
            if (lane == 0) nsh[e] = n;
            int b = n >> 12, hw = n & 4095;
            const float* zp = z + (size_t)b * DIM * HWX + hw;
            zsh[e][lane]      = zp[(size_t)lane * HWX];
            zsh[e][lane + 64] = zp[(size_t)(lane + 64) * HWX];
        }

        float best[4]; int bi[4];
        #pragma unroll
        for (int i = 0; i < 4; ++i) { best[i] = 3.0e38f; bi[i] = 0; }

        for (int tile = 0; tile < 8; ++tile) {
            __syncthreads();    // zsh/nsh ready (tile 0); prev esh reads done (tile>0)
            {   // stage 64 codes x 128 dims fp32, coalesced b128; esq into col 128
                const float4* gsrc = (const float4*)(emb + (size_t)tile * 64 * DIM);
                #pragma unroll
                for (int jj = 0; jj < 8; ++jj) {
                    int f = jj * 256 + t;
                    int k = f >> 5, q = f & 31;
                    float4 v = gsrc[f];
                    *(float4*)&esh[k][q * 4] = v;
                }
                if (t < 64) esh[t][128] = esq[tile * 64 + t];
            }
            __syncthreads();

            // 4 entries (te + 16i) x 4 codes (tc*4 + j): 64 FMA per 8 b128 reads
            float acc[4][4];
            #pragma unroll
            for (int i = 0; i < 4; ++i)
                #pragma unroll
                for (int j = 0; j < 4; ++j) acc[i][j] = 0.f;

            #pragma unroll 4
            for (int c4 = 0; c4 < 32; ++c4) {
                float4 zv[4], ev[4];
                #pragma unroll
                for (int i = 0; i < 4; ++i) zv[i] = *(const float4*)&zsh[te + 16 * i][c4 * 4];
                #pragma unroll
                for (int j = 0; j < 4; ++j) ev[j] = *(const float4*)&esh[tc * 4 + j][c4 * 4];
                #pragma unroll
                for (int i = 0; i < 4; ++i)
                    #pragma unroll
                    for (int j = 0; j < 4; ++j) {
                        acc[i][j] = fmaf(zv[i].x, ev[j].x, acc[i][j]);
                        acc[i][j] = fmaf(zv[i].y, ev[j].y, acc[i][j]);
                        acc[i][j] = fmaf(zv[i].z, ev[j].z, acc[i][j]);
                        acc[i][j] = fmaf(zv[i].w, ev[j].w, acc[i][j]);
                    }
            }
            #pragma unroll
            for (int j = 0; j < 4; ++j) {
                int k = tile * 64 + tc * 4 + j;
                float es = esh[tc * 4 + j][128];
                #pragma unroll
                for (int i = 0; i < 4; ++i) {
                    float s = fmaf(-2.f, acc[i][j], es);
                    if (s < best[i]) { best[i] = s; bi[i] = k; }  // k ascending per thread
                }
            }
        }
        __syncthreads();   // all esh/zsh reads done
        #pragma unroll
        for (int i = 0; i < 4; ++i) { rs[te + 16 * i][tc] = best[i]; ri[te + 16 * i][tc] = bi[i]; }
        __syncthreads();
        if (t < 64) {
            float bs = rs[t][0]; int bk = ri[t][0];
            #pragma unroll
            for (int q = 1; q < 16; ++q) {     // lex (s,k): first-min over all 512 codes
                float s2 = rs[t][q]; int k2 = ri[t][q];
                bool take = (s2 < bs) || (s2 == bs && k2 < bk);
                bs = take ? s2 : bs;
                bk = take ? k2 : bk;
            }
            gidx[nsh[t]] = bk;
        }
        __syncthreads();   // protect zsh/nsh for next grid-stride round
    }
}

// ---------------- gather: out[b,c,hw] = emb[gidx[n], c] ----------------
__global__ __launch_bounds__(256) void gather_kernel(const float* __restrict__ emb,
                                                     const int* __restrict__ gidx,
                                                     float* __restrict__ out) {
    int n = blockIdx.x * 256 + threadIdx.x;
    int b = n >> 12, hw = n & 4095;
    int idx = gidx[n];
    float* ob = out + (size_t)b * DIM * HWX + hw;
    const float4* sel = (const float4*)(emb + (size_t)idx * DIM);
    #pragma unroll
    for (int c4 = 0; c4 < DIM / 4; ++c4) {
        float4 v = sel[c4];
        ob[(size_t)(4 * c4 + 0) * HWX] = v.x;
        ob[(size_t)(4 * c4 + 1) * HWX] = v.y;
        ob[(size_t)(4 * c4 + 2) * HWX] = v.z;
        ob[(size_t)(4 * c4 + 3) * HWX] = v.w;
    }
}

// ---------------- legacy fallback (round-1, verified) ----------------
__global__ void esq_kernel(const float* __restrict__ emb, float* __restrict__ e_sq) {
    int k = blockIdx.x * blockDim.x + threadIdx.x;
    if (k < NUM_EMB) {
        const float4* row = (const float4*)(emb + k * DIM);
        float s0 = 0.f, s1 = 0.f, s2 = 0.f, s3 = 0.f;
        #pragma unroll
        for (int c = 0; c < DIM / 4; ++c) {
            float4 v = row[c];
            s0 = fmaf(v.x, v.x, s0); s1 = fmaf(v.y, v.y, s1);
            s2 = fmaf(v.z, v.z, s2); s3 = fmaf(v.w, v.w, s3);
        }
        e_sq[k] = (s0 + s1) + (s2 + s3);
    }
}

__global__ __launch_bounds__(256) void vq_kernel(const float* __restrict__ z,
                                                 const float* __restrict__ emb,
                                                 const float* __restrict__ e_sq,
                                                 float* __restrict__ out) {
    int n = blockIdx.x * 256 + threadIdx.x;
    int b = n >> 12, hw = n & 4095;
    const float* zb = z + (size_t)b * DIM * HWX + hw;
    float zr[DIM];
    #pragma unroll
    for (int c = 0; c < DIM; ++c) zr[c] = zb[(size_t)c * HWX];
    float best = FLT_MAX; int besti = 0;
    for (int k = 0; k < NUM_EMB; ++k) {
        const float4* er = (const float4*)(emb + k * DIM);
        float d0 = 0.f, d1 = 0.f, d2 = 0.f, d3 = 0.f;
        #pragma unroll
        for (int c = 0; c < DIM / 4; ++c) {
            float4 e = er[c];
            d0 = fmaf(zr[4 * c + 0], e.x, d0);
            d1 = fmaf(zr[4 * c + 1], e.y, d1);
            d2 = fmaf(zr[4 * c + 2], e.z, d2);
            d3 = fmaf(zr[4 * c + 3], e.w, d3);
        }
        float s = e_sq[k] - 2.f * ((d0 + d1) + (d2 + d3));
        if (s < best) { best = s; besti = k; }
    }
    float* ob = out + (size_t)b * DIM * HWX + hw;
    const float4* sel = (const float4*)(emb + (size_t)besti * DIM);
    #pragma unroll
    for (int c4 = 0; c4 < DIM / 4; ++c4) {
        float4 v = sel[c4];
        ob[(size_t)(4 * c4 + 0) * HWX] = v.x;
        ob[(size_t)(4 * c4 + 1) * HWX] = v.y;
        ob[(size_t)(4 * c4 + 2) * HWX] = v.z;
        ob[(size_t)(4 * c4 + 3) * HWX] = v.w;
    }
}

extern "C" void kernel_launch(void* const* d_in, const int* in_sizes, int n_in,
                              void* d_out, int out_size, void* d_ws, size_t ws_size,
                              hipStream_t stream) {
    const float* z   = (const float*)d_in[0];   // (32,128,64,64) fp32
    const float* emb = (const float*)d_in[1];   // (512,128) fp32
    float* out = (float*)d_out;

    if (ws_size < WS_NEED) {
        // fallback: verified round-1 path
        float* e_sq = (float*)d_ws;
        esq_kernel<<<(NUM_EMB + 255) / 256, 256, 0, stream>>>(emb, e_sq);
        vq_kernel<<<NPOS / 256, 256, 0, stream>>>(z, emb, e_sq, out);
        return;
    }

    char* ws = (char*)d_ws;
    _Float16* zt  = (_Float16*)(ws + WS_ZT);
    _Float16* e16 = (_Float16*)(ws + WS_E16);
    float*    esq = (float*)(ws + WS_ESQ);
    int*      gidx = (int*)(ws + WS_GIDX);
    int*      wl   = (int*)(ws + WS_WL);
    int*      cnt  = (int*)(ws + WS_CNT);

    prep_kernel<<<2, 256, 0, stream>>>(emb, e16, esq, cnt);
    transpose_kernel<<<NPOS / 64, 256, 0, stream>>>(z, zt);
    gemm_argmin<<<NPOS / 128, 256, 0, stream>>>(zt, e16, esq, gidx, wl, cnt);
    refine_kernel<<<256, 256, 0, stream>>>(z, emb, esq, wl, cnt, gidx);
    gather_kernel<<<NPOS / 256, 256, 0, stream>>>(emb, gidx, out);
}

// Round 5
// 261.112 us; speedup vs baseline: 2.5500x; 1.0326x over previous
//
#include <hip/hip_runtime.h>
#include <float.h>

#define NUM_EMB 512
#define DIM     128
#define HWX     4096          // 64*64 spatial per batch
#define NPOS    (32 * 4096)   // 131072 positions
#define MARGIN  0.35f         // fp16 noise (13+ sigma) + packed-score quantization (0.064)

// ---------------- workspace layout (bytes) ----------------
#define WS_ZT    ((size_t)0)                    // 131072*128 fp16 = 33554432
#define WS_E16   ((size_t)33554432)             // 512*128 fp16   = 131072
#define WS_ESQ   ((size_t)33685504)             // 512 fp32       = 2048
#define WS_GIDX  ((size_t)33687552)             // 131072 int     = 524288
#define WS_WL    ((size_t)34211840)             // 131072 int     = 524288
#define WS_CNT   ((size_t)34736128)             // counter        = 256
#define WS_NEED  ((size_t)34736384)

using half8 = __attribute__((ext_vector_type(8))) _Float16;
using f32x4 = __attribute__((ext_vector_type(4))) float;

// ---------------- prep: e16[k][c], exact e_sq, zero counter ----------------
__global__ void prep_kernel(const float* __restrict__ emb, _Float16* __restrict__ e16,
                            float* __restrict__ esq, int* __restrict__ cnt) {
    int k = blockIdx.x * blockDim.x + threadIdx.x;
    if (k == 0) *cnt = 0;
    if (k < NUM_EMB) {
        const float4* row = (const float4*)(emb + (size_t)k * DIM);
        _Float16* dst = e16 + (size_t)k * DIM;
        float s0 = 0.f, s1 = 0.f, s2 = 0.f, s3 = 0.f;
        #pragma unroll
        for (int c = 0; c < DIM / 4; ++c) {
            float4 v = row[c];
            s0 = fmaf(v.x, v.x, s0);
            s1 = fmaf(v.y, v.y, s1);
            s2 = fmaf(v.z, v.z, s2);
            s3 = fmaf(v.w, v.w, s3);
            dst[4 * c + 0] = (_Float16)v.x;
            dst[4 * c + 1] = (_Float16)v.y;
            dst[4 * c + 2] = (_Float16)v.z;
            dst[4 * c + 3] = (_Float16)v.w;
        }
        esq[k] = (s0 + s1) + (s2 + s3);   // identical math to round-1 (verified exact vs numpy)
    }
}

// ---------------- transpose: z (b,c,hw) fp32 -> zt (n,c) fp16 ----------------
__global__ __launch_bounds__(256) void transpose_kernel(const float* __restrict__ z,
                                                        _Float16* __restrict__ zt) {
    __shared__ __align__(16) _Float16 sh[64 * 136];   // 64 rows, 272B stride (pad 16B)
    int t = threadIdx.x;
    int n0 = blockIdx.x * 64;
    int b = n0 >> 12, hw0 = n0 & 4095;
    int q = t >> 6, l = t & 63;
    const float* src = z + (size_t)b * DIM * HWX + hw0 + l;
    #pragma unroll
    for (int i = 0; i < 32; ++i) {
        int c = q * 32 + i;
        float v = src[(size_t)c * HWX];           // 64 consecutive lanes -> coalesced
        sh[l * 136 + c] = (_Float16)v;
    }
    __syncthreads();
    #pragma unroll
    for (int r = 0; r < 4; ++r) {
        int f = r * 4096 + t * 16;                // byte offset in 16KB output tile
        int row = f >> 8, colb = f & 255;
        float4 v = *(const float4*)((const char*)sh + row * 272 + colb);
        *(float4*)((char*)(zt + (size_t)(n0 + row) * DIM) + colb) = v;  // contiguous writes
    }
}

// ---------------- gemm v2: LDS-free, barrier-free MFMA argmin ----------------
// Block = 128 positions x all 512 codes. 4 waves: (wm in {0,1}) x (wn in {0,1});
// wave owns 64 pos x 32 codes per 64-code tile (8 tiles). A-fragments global->reg
// once (zt read exactly once, 64B-sector coalesced). B-fragments stream from the
// 128KB L2-hot e16 (8 dwordx4 in flight per tile, NO __syncthreads in the loop).
// Scores packed (score & ~511) | code: min-reductions carry the index for free;
// quantization error <=0.032 is absorbed by MARGIN (flagged -> exact refine).
__global__ __launch_bounds__(256) void gemm_argmin(const _Float16* __restrict__ zt,
                                                   const _Float16* __restrict__ e16,
                                                   const float* __restrict__ esq,
                                                   int* __restrict__ gidx,
                                                   int* __restrict__ wl,
                                                   int* __restrict__ cnt) {
    __shared__ float mB1[2][128];
    __shared__ float mB2[2][128];

    int t = threadIdx.x;
    int lane = t & 63, wave = t >> 6;
    int wm = wave & 1, wn = wave >> 1;
    int quad = lane >> 4, l15 = lane & 15;
    int n0 = blockIdx.x * 128;

    // ---- A fragments: af[mt][kc], row = n0+wm*64+mt*16+l15, bytes kc*64+quad*16
    half8 af[4][4];
    {
        const char* zb = (const char*)zt + ((size_t)(n0 + wm * 64 + l15) << 8) + quad * 16;
        #pragma unroll
        for (int mt = 0; mt < 4; ++mt)
            #pragma unroll
            for (int kc = 0; kc < 4; ++kc)
                af[mt][kc] = *(const half8*)(zb + mt * 4096 + kc * 64);
    }

    // ---- esq preload: esqv[tile][nt] for code = tile*64 + wn*32 + nt*16 + l15
    float esqv[8][2];
    #pragma unroll
    for (int tile = 0; tile < 8; ++tile)
        #pragma unroll
        for (int nt = 0; nt < 2; ++nt)
            esqv[tile][nt] = esq[tile * 64 + wn * 32 + nt * 16 + l15];

    float b1[16], b2[16];
    #pragma unroll
    for (int s = 0; s < 16; ++s) { b1[s] = 3.0e38f; b2[s] = 3.0e38f; }

    const char* ebase = (const char*)e16 + ((size_t)(wn * 32 + l15) << 8) + quad * 16;

    #pragma unroll 2
    for (int tile = 0; tile < 8; ++tile) {
        // ---- B fragments: 8 dwordx4 from L2-hot e16, all in flight
        half8 bf[2][4];
        {
            const char* eb = ebase + (size_t)tile * 64 * 256;
            #pragma unroll
            for (int nt = 0; nt < 2; ++nt)
                #pragma unroll
                for (int kc = 0; kc < 4; ++kc)
                    bf[nt][kc] = *(const half8*)(eb + nt * 4096 + kc * 64);
        }

        f32x4 acc[4][2];
        #pragma unroll
        for (int mt = 0; mt < 4; ++mt)
            #pragma unroll
            for (int nt = 0; nt < 2; ++nt)
                acc[mt][nt] = (f32x4){0.f, 0.f, 0.f, 0.f};

        #pragma unroll
        for (int kc = 0; kc < 4; ++kc)
            #pragma unroll
            for (int mt = 0; mt < 4; ++mt)
                #pragma unroll
                for (int nt = 0; nt < 2; ++nt)
                    acc[mt][nt] = __builtin_amdgcn_mfma_f32_16x16x32_f16(af[mt][kc], bf[nt][kc], acc[mt][nt], 0, 0, 0);

        // ---- packed top-2: ~5 VALU/score, no index cndmask
        #pragma unroll
        for (int nt = 0; nt < 2; ++nt) {
            unsigned code = (unsigned)(tile * 64 + wn * 32 + nt * 16 + l15);
            float es = esqv[tile][nt];
            #pragma unroll
            for (int mt = 0; mt < 4; ++mt)
                #pragma unroll
                for (int r = 0; r < 4; ++r) {
                    int s = mt * 4 + r;
                    float sc = fmaf(-2.0f, acc[mt][nt][r], es);
                    float p = __uint_as_float((__float_as_uint(sc) & 0xFFFFFE00u) | code);
                    b2[s] = fminf(b2[s], fmaxf(b1[s], p));
                    b1[s] = fminf(b1[s], p);
                }
        }
    }

    // ---- butterfly top-2 merge across the 16 lanes (l15) sharing each position
    #pragma unroll
    for (int d = 1; d < 16; d <<= 1) {
        #pragma unroll
        for (int s = 0; s < 16; ++s) {
            float ob1 = __shfl_xor(b1[s], d, 64);
            float ob2 = __shfl_xor(b2[s], d, 64);
            b2[s] = fminf(fminf(b2[s], ob2), fmaxf(b1[s], ob1));
            b1[s] = fminf(b1[s], ob1);
        }
    }
    if (l15 == 0) {
        #pragma unroll
        for (int s = 0; s < 16; ++s) {
            int m = wm * 64 + (s >> 2) * 16 + quad * 4 + (s & 3);
            mB1[wn][m] = b1[s];
            mB2[wn][m] = b2[s];
        }
    }
    __syncthreads();
    if (t < 128) {
        float a1 = mB1[0][t], c1 = mB1[1][t];
        float f1 = fminf(a1, c1);
        float f2 = fminf(fminf(mB2[0][t], mB2[1][t]), fmaxf(a1, c1));
        gidx[n0 + t] = (int)(__float_as_uint(f1) & 511u);
        if (f2 - f1 < MARGIN) {
            int p = atomicAdd(cnt, 1);
            wl[p] = n0 + t;
        }
    }
}

// ---------------- refine v3: count-proportional GEMM-style exact rescan ----------------
__global__ __launch_bounds__(256) void refine_kernel(const float* __restrict__ z,
                                                     const float* __restrict__ emb,
                                                     const float* __restrict__ esq,
                                                     const int* __restrict__ wl,
                                                     const int* __restrict__ cnt,
                                                     int* __restrict__ gidx) {
    __shared__ __align__(16) float zsh[64][132];   // [entry][dim]
    __shared__ __align__(16) float esh[64][132];   // [code][dim], col 128 = esq
    __shared__ float rs[64][16];
    __shared__ int   ri[64][16];
    __shared__ int   nsh[64];

    int t = threadIdx.x, lane = t & 63, wave = t >> 6;
    int te = t & 15, tc = t >> 4;                  // entry group / code group
    int count = *cnt;

    for (int base = blockIdx.x * 64; base < count; base += 256 * 64) {
        for (int j16 = 0; j16 < 16; ++j16) {
            int e = wave * 16 + j16;
            int ge = base + e;
            if (ge > count - 1) ge = count - 1;    // clamp: duplicate entries benign
            int n = wl[ge];
            if (lane == 0) nsh[e] = n;
            int b = n >> 12, hw = n & 4095;
            const float* zp = z + (size_t)b * DIM * HWX + hw;
            zsh[e][lane]      = zp[(size_t)lane * HWX];
            zsh[e][lane + 64] = zp[(size_t)(lane + 64) * HWX];
        }

        float best[4]; int bi[4];
        #pragma unroll
        for (int i = 0; i < 4; ++i) { best[i] = 3.0e38f; bi[i] = 0; }

        for (int tile = 0; tile < 8; ++tile) {
            __syncthreads();    // zsh/nsh ready (tile 0); prev esh reads done (tile>0)
            {   // stage 64 codes x 128 dims fp32, coalesced b128; esq into col 128
                const float4* gsrc = (const float4*)(emb + (size_t)tile * 64 * DIM);
                #pragma unroll
                for (int jj = 0; jj < 8; ++jj) {
                    int f = jj * 256 + t;
                    int k = f >> 5, q = f & 31;
                    float4 v = gsrc[f];
                    *(float4*)&esh[k][q * 4] = v;
                }
                if (t < 64) esh[t][128] = esq[tile * 64 + t];
            }
            __syncthreads();

            float acc[4][4];
            #pragma unroll
            for (int i = 0; i < 4; ++i)
                #pragma unroll
                for (int j = 0; j < 4; ++j) acc[i][j] = 0.f;

            #pragma unroll 4
            for (int c4 = 0; c4 < 32; ++c4) {
                float4 zv[4], ev[4];
                #pragma unroll
                for (int i = 0; i < 4; ++i) zv[i] = *(const float4*)&zsh[te + 16 * i][c4 * 4];
                #pragma unroll
                for (int j = 0; j < 4; ++j) ev[j] = *(const float4*)&esh[tc * 4 + j][c4 * 4];
                #pragma unroll
                for (int i = 0; i < 4; ++i)
                    #pragma unroll
                    for (int j = 0; j < 4; ++j) {
                        acc[i][j] = fmaf(zv[i].x, ev[j].x, acc[i][j]);
                        acc[i][j] = fmaf(zv[i].y, ev[j].y, acc[i][j]);
                        acc[i][j] = fmaf(zv[i].z, ev[j].z, acc[i][j]);
                        acc[i][j] = fmaf(zv[i].w, ev[j].w, acc[i][j]);
                    }
            }
            #pragma unroll
            for (int j = 0; j < 4; ++j) {
                int k = tile * 64 + tc * 4 + j;
                float es = esh[tc * 4 + j][128];
                #pragma unroll
                for (int i = 0; i < 4; ++i) {
                    float s = fmaf(-2.f, acc[i][j], es);
                    if (s < best[i]) { best[i] = s; bi[i] = k; }  // k ascending per thread
                }
            }
        }
        __syncthreads();   // all esh/zsh reads done
        #pragma unroll
        for (int i = 0; i < 4; ++i) { rs[te + 16 * i][tc] = best[i]; ri[te + 16 * i][tc] = bi[i]; }
        __syncthreads();
        if (t < 64) {
            float bs = rs[t][0]; int bk = ri[t][0];
            #pragma unroll
            for (int q = 1; q < 16; ++q) {     // lex (s,k): first-min over all 512 codes
                float s2 = rs[t][q]; int k2 = ri[t][q];
                bool take = (s2 < bs) || (s2 == bs && k2 < bk);
                bs = take ? s2 : bs;
                bk = take ? k2 : bk;
            }
            gidx[nsh[t]] = bk;
        }
        __syncthreads();   // protect zsh/nsh for next grid-stride round
    }
}

// ---------------- gather: out[b,c,hw] = emb[gidx[n], c] ----------------
__global__ __launch_bounds__(256) void gather_kernel(const float* __restrict__ emb,
                                                     const int* __restrict__ gidx,
                                                     float* __restrict__ out) {
    int n = blockIdx.x * 256 + threadIdx.x;
    int b = n >> 12, hw = n & 4095;
    int idx = gidx[n];
    float* ob = out + (size_t)b * DIM * HWX + hw;
    const float4* sel = (const float4*)(emb + (size_t)idx * DIM);
    #pragma unroll
    for (int c4 = 0; c4 < DIM / 4; ++c4) {
        float4 v = sel[c4];
        ob[(size_t)(4 * c4 + 0) * HWX] = v.x;
        ob[(size_t)(4 * c4 + 1) * HWX] = v.y;
        ob[(size_t)(4 * c4 + 2) * HWX] = v.z;
        ob[(size_t)(4 * c4 + 3) * HWX] = v.w;
    }
}

// ---------------- legacy fallback (round-1, verified) ----------------
__global__ void esq_kernel(const float* __restrict__ emb, float* __restrict__ e_sq) {
    int k = blockIdx.x * blockDim.x + threadIdx.x;
    if (k < NUM_EMB) {
        const float4* row = (const float4*)(emb + k * DIM);
        float s0 = 0.f, s1 = 0.f, s2 = 0.f, s3 = 0.f;
        #pragma unroll
        for (int c = 0; c < DIM / 4; ++c) {
            float4 v = row[c];
            s0 = fmaf(v.x, v.x, s0); s1 = fmaf(v.y, v.y, s1);
            s2 = fmaf(v.z, v.z, s2); s3 = fmaf(v.w, v.w, s3);
        }
        e_sq[k] = (s0 + s1) + (s2 + s3);
    }
}

__global__ __launch_bounds__(256) void vq_kernel(const float* __restrict__ z,
                                                 const float* __restrict__ emb,
                                                 const float* __restrict__ e_sq,
                                                 float* __restrict__ out) {
    int n = blockIdx.x * 256 + threadIdx.x;
    int b = n >> 12, hw = n & 4095;
    const float* zb = z + (size_t)b * DIM * HWX + hw;
    float zr[DIM];
    #pragma unroll
    for (int c = 0; c < DIM; ++c) zr[c] = zb[(size_t)c * HWX];
    float best = FLT_MAX; int besti = 0;
    for (int k = 0; k < NUM_EMB; ++k) {
        const float4* er = (const float4*)(emb + k * DIM);
        float d0 = 0.f, d1 = 0.f, d2 = 0.f, d3 = 0.f;
        #pragma unroll
        for (int c = 0; c < DIM / 4; ++c) {
            float4 e = er[c];
            d0 = fmaf(zr[4 * c + 0], e.x, d0);
            d1 = fmaf(zr[4 * c + 1], e.y, d1);
            d2 = fmaf(zr[4 * c + 2], e.z, d2);
            d3 = fmaf(zr[4 * c + 3], e.w, d3);
        }
        float s = e_sq[k] - 2.f * ((d0 + d1) + (d2 + d3));
        if (s < best) { best = s; besti = k; }
    }
    float* ob = out + (size_t)b * DIM * HWX + hw;
    const float4* sel = (const float4*)(emb + (size_t)besti * DIM);
    #pragma unroll
    for (int c4 = 0; c4 < DIM / 4; ++c4) {
        float4 v = sel[c4];
        ob[(size_t)(4 * c4 + 0) * HWX] = v.x;
        ob[(size_t)(4 * c4 + 1) * HWX] = v.y;
        ob[(size_t)(4 * c4 + 2) * HWX] = v.z;
        ob[(size_t)(4 * c4 + 3) * HWX] = v.w;
    }
}

extern "C" void kernel_launch(void* const* d_in, const int* in_sizes, int n_in,
                              void* d_out, int out_size, void* d_ws, size_t ws_size,
                              hipStream_t stream) {
    const float* z   = (const float*)d_in[0];   // (32,128,64,64) fp32
    const float* emb = (const float*)d_in[1];   // (512,128) fp32
    float* out = (float*)d_out;

    if (ws_size < WS_NEED) {
        // fallback: verified round-1 path
        float* e_sq = (float*)d_ws;
        esq_kernel<<<(NUM_EMB + 255) / 256, 256, 0, stream>>>(emb, e_sq);
        vq_kernel<<<NPOS / 256, 256, 0, stream>>>(z, emb, e_sq, out);
        return;
    }

    char* ws = (char*)d_ws;
    _Float16* zt  = (_Float16*)(ws + WS_ZT);
    _Float16* e16 = (_Float16*)(ws + WS_E16);
    float*    esq = (float*)(ws + WS_ESQ);
    int*      gidx = (int*)(ws + WS_GIDX);
    int*      wl   = (int*)(ws + WS_WL);
    int*      cnt  = (int*)(ws + WS_CNT);

    prep_kernel<<<2, 256, 0, stream>>>(emb, e16, esq, cnt);
    transpose_kernel<<<NPOS / 64, 256, 0, stream>>>(z, zt);
    gemm_argmin<<<NPOS / 128, 256, 0, stream>>>(zt, e16, esq, gidx, wl, cnt);
    refine_kernel<<<256, 256, 0, stream>>>(z, emb, esq, wl, cnt, gidx);
    gather_kernel<<<NPOS / 256, 256, 0, stream>>>(emb, gidx, out);
}